// Round 3
// baseline (115.079 us; speedup 1.0000x reference)
//
#include <hip/hip_runtime.h>

// YOLO-style loss, MI355X.
// loss = (2*sum((p_box - t_box)^2) + sum(mask ? CE : 0)) / 512
// box channels: 0..3 and 24..27 ; cls channels: 8..27 (24..27 double-used, per reference)
#define C_CLS 20
#define D_CH 28
#define BATCH_N 512
#define CELLS (BATCH_N * 28 * 28)     // 401408
#define BLOCK 256
#define CPB 256                       // cells per block
#define NBLOCKS (CELLS / CPB)         // 1568, exact

// LDS layout: one 128B row (32 floats) per cell; 8 float4 slots per row.
// Logical float4 c4 (0..6) of cell i lives at slot (c4 ^ (i & 7)) — XOR swizzle
// makes both the staging ds_write_b128 and the per-cell ds_read_b128 bank-conflict-free.

__global__ __launch_bounds__(BLOCK) void yolo_fused_kernel(
    const float* __restrict__ preds,
    const float* __restrict__ tgts,
    float* __restrict__ out)
{
    __shared__ float ldsP[CPB * 32];   // 32 KB
    __shared__ float ldsT[CPB * 32];   // 32 KB

    const int tid = threadIdx.x;
    const size_t base = (size_t)blockIdx.x * (CPB * D_CH);
    const float4* gp = reinterpret_cast<const float4*>(preds + base);
    const float4* gt = reinterpret_cast<const float4*>(tgts + base);

    // ---- coalesced global load: lane stride 16B, 7 float4 per tensor per thread ----
    float4 vp[7], vt[7];
    #pragma unroll
    for (int k = 0; k < 7; ++k) vp[k] = gp[tid + BLOCK * k];
    #pragma unroll
    for (int k = 0; k < 7; ++k) vt[k] = gt[tid + BLOCK * k];

    // ---- swizzled LDS scatter ----
    #pragma unroll
    for (int k = 0; k < 7; ++k) {
        const int idx  = tid + BLOCK * k;      // float4 index within block region
        const int cell = idx / 7;
        const int c4   = idx - cell * 7;
        const int slot = c4 ^ (cell & 7);
        *reinterpret_cast<float4*>(&ldsP[cell * 32 + slot * 4]) = vp[k];
        *reinterpret_cast<float4*>(&ldsT[cell * 32 + slot * 4]) = vt[k];
    }
    __syncthreads();

    // ---- gather own cell (thread tid <-> cell tid), conflict-free swizzled reads ----
    float p[D_CH], t[D_CH];
    #pragma unroll
    for (int c4 = 0; c4 < 7; ++c4) {
        const int slot = c4 ^ (tid & 7);
        float4 a = *reinterpret_cast<const float4*>(&ldsP[tid * 32 + slot * 4]);
        float4 b = *reinterpret_cast<const float4*>(&ldsT[tid * 32 + slot * 4]);
        p[4*c4+0] = a.x; p[4*c4+1] = a.y; p[4*c4+2] = a.z; p[4*c4+3] = a.w;
        t[4*c4+0] = b.x; t[4*c4+1] = b.y; t[4*c4+2] = b.z; t[4*c4+3] = b.w;
    }

    // ---- coord loss: channels 0..3 and 24..27 ----
    float coord = 0.0f;
    #pragma unroll
    for (int j = 0; j < 4; ++j) {
        float d0 = p[j]      - t[j];      coord = fmaf(d0, d0, coord);
        float d1 = p[24 + j] - t[24 + j]; coord = fmaf(d1, d1, coord);
    }

    // ---- class CE: channels 8..27 ----
    float m    = -INFINITY;
    float tsum = 0.0f;
    float tmax = -INFINITY;
    int   lab  = 0;
    #pragma unroll
    for (int j = 0; j < C_CLS; ++j) {
        float pc = p[8 + j];
        float tc = t[8 + j];
        m = fmaxf(m, pc);
        tsum += tc;
        if (tc > tmax) { tmax = tc; lab = j; }   // strict > == first-max (jnp.argmax)
    }
    float se = 0.0f;
    #pragma unroll
    for (int j = 0; j < C_CLS; ++j) se += __expf(p[8 + j] - m);
    float plab = p[8];
    #pragma unroll
    for (int j = 1; j < C_CLS; ++j) plab = (lab == j) ? p[8 + j] : plab;
    float ce = -(plab - m - __logf(se));

    float loss = 2.0f * coord + ((tsum > 0.0f) ? ce : 0.0f);

    // ---- wave + block reduce, one atomic per block ----
    #pragma unroll
    for (int off = 32; off > 0; off >>= 1) loss += __shfl_down(loss, off, 64);

    __shared__ float sm[BLOCK / 64];
    const int wid  = tid >> 6;
    const int lane = tid & 63;
    if (lane == 0) sm[wid] = loss;
    __syncthreads();
    if (tid == 0) {
        float s = sm[0] + sm[1] + sm[2] + sm[3];
        atomicAdd(out, s * (1.0f / (float)BATCH_N));
    }
}

extern "C" void kernel_launch(void* const* d_in, const int* in_sizes, int n_in,
                              void* d_out, int out_size, void* d_ws, size_t ws_size,
                              hipStream_t stream)
{
    const float* preds = (const float*)d_in[0];
    const float* tgts  = (const float*)d_in[1];
    float* out = (float*)d_out;

    hipMemsetAsync(out, 0, (size_t)out_size * sizeof(float), stream);  // d_out poisoned 0xAA
    yolo_fused_kernel<<<NBLOCKS, BLOCK, 0, stream>>>(preds, tgts, out);
}